// Round 2
// baseline (85072.455 us; speedup 1.0000x reference)
//
#include <hip/hip_runtime.h>

#define NNODE 101
#define DIM   128
#define NHEAD 8
#define NSTEP 150
#define BTOT  2048
#define ENCP  132          // padded enc row stride in LDS

// packed-weight ws layout (floats)
#define OFF_FCP   0
#define OFF_FC1P  16384
#define OFF_MWP   32768
#define OFF_MVP   49152
#define OFF_FP    65536
#define OFF_MKP   81920
#define OFF_FCC   98304
#define NORM_PROB 0.08838834764831845f

// R13: latency-attack on the R12 chassis (1 elem / 256 thr / 2 blocks/CU):
// (a) lgkmcnt-only barriers in the step loop (no vmcnt drain -> global loads
//     survive across phase boundaries);
// (b) fc/fc1 held PERMANENTLY in registers (32 float4/thread, step-invariant
//     addresses) -> PH1 has zero global traffic;
// (c) next-phase weight prefetch: mw issued during PH1, mk during PH2 (idle
//     half), mv during PH4, F during PH5b;
// (d) PH3/PH5 spread over all 256 threads (4 SIMDs), PH5b/PH6 moved to waves
//     2-3 to balance VGPR load (waves 0-1 hold fc, waves 2-3 hold fc1).
// Every fma chain keeps its exact order -> bit-exact vs R12.
struct __align__(16) BS {
  float enc[NNODE * ENCP];              // 53,328 B
  float in_[DIM], pl[DIM], dec[DIM], q[DIM], attn[DIM], op[DIM];
  float U[1888];                        // QK/ZR: h*132+i ; CMP: 1056+h*104+n
  float sc[1212];                       // SC: n*12+h ; SRED: n*12+k
  float mask[NNODE], mask1[NNODE], dem[NNODE];
  float cap, lp;
  int   idx;
};                                      // ~70,032 B total

#define EL(n,i)     S.enc[(n)*ENCP + (i)]
#define QK(h,i)     S.U[(h)*132 + (i)]
#define ZR(h,i)     S.U[(h)*132 + (i)]
#define CMP(h,n)    S.U[1056 + (h)*104 + (n)]
#define SC(n,h)     S.sc[(n)*12 + (h)]
#define SRED(n,k)   S.sc[(n)*12 + (k)]

// intra-step barrier: orders LDS only; global loads stay in flight
#define BAR() asm volatile("s_waitcnt lgkmcnt(0)\n\ts_barrier" ::: "memory")

// Pack all weights as float4 panels: P[i4*128 + j] = {wT[i4*4+0][j], .., wT[i4*4+3][j]}
__global__ void prep_weights(const float* __restrict__ fc_w,
                             const float* __restrict__ fc1_w,
                             const float* __restrict__ mw_w,
                             const float* __restrict__ mv_w,
                             const float* __restrict__ mfc_w,
                             const float* __restrict__ pk_w,
                             const float* __restrict__ mk_w,
                             float* __restrict__ ws) {
  int x = blockIdx.x * 256 + threadIdx.x;
  if (x < 4096) {                      // fcP
    int i4 = x >> 7, j = x & 127;
    float4 v = make_float4(fc_w[j * 129 + i4 * 4 + 0], fc_w[j * 129 + i4 * 4 + 1],
                           fc_w[j * 129 + i4 * 4 + 2], fc_w[j * 129 + i4 * 4 + 3]);
    *(float4*)&ws[OFF_FCP + x * 4] = v; return;
  }
  x -= 4096;
  if (x < 4096) {                      // fc1P
    int i4 = x >> 7, j = x & 127;
    float4 v = make_float4(fc1_w[j * 128 + i4 * 4 + 0], fc1_w[j * 128 + i4 * 4 + 1],
                           fc1_w[j * 128 + i4 * 4 + 2], fc1_w[j * 128 + i4 * 4 + 3]);
    *(float4*)&ws[OFF_FC1P + x * 4] = v; return;
  }
  x -= 4096;
  if (x < 4096) {                      // mwP
    int i4 = x >> 7, j = x & 127;
    float4 v = make_float4(mw_w[j * 128 + i4 * 4 + 0], mw_w[j * 128 + i4 * 4 + 1],
                           mw_w[j * 128 + i4 * 4 + 2], mw_w[j * 128 + i4 * 4 + 3]);
    *(float4*)&ws[OFF_MWP + x * 4] = v; return;
  }
  x -= 4096;
  if (x < 4096) {                      // mvP
    int i4 = x >> 7, j = x & 127;
    float4 v = make_float4(mv_w[j * 128 + i4 * 4 + 0], mv_w[j * 128 + i4 * 4 + 1],
                           mv_w[j * 128 + i4 * 4 + 2], mv_w[j * 128 + i4 * 4 + 3]);
    *(float4*)&ws[OFF_MVP + x * 4] = v; return;
  }
  x -= 4096;
  if (x < 4096) {                      // FP : F[i2][j] = sum_d mfc[d][i2]*pk[d][j]
    int i4 = x >> 7, j = x & 127;
    float a[4] = {0.f, 0.f, 0.f, 0.f};
    for (int d = 0; d < 128; ++d) {
      float p = pk_w[d * 128 + j];
      a[0] = fmaf(mfc_w[d * 128 + i4 * 4 + 0], p, a[0]);
      a[1] = fmaf(mfc_w[d * 128 + i4 * 4 + 1], p, a[1]);
      a[2] = fmaf(mfc_w[d * 128 + i4 * 4 + 2], p, a[2]);
      a[3] = fmaf(mfc_w[d * 128 + i4 * 4 + 3], p, a[3]);
    }
    *(float4*)&ws[OFF_FP + x * 4] = make_float4(a[0], a[1], a[2], a[3]); return;
  }
  x -= 4096;
  if (x < 4096) {                      // mkP
    int hk = x >> 7, j = x & 127;
    int h = hk >> 2, k4 = hk & 3;
    float4 v = make_float4(mk_w[(h * 16 + k4 * 4 + 0) * 128 + j],
                           mk_w[(h * 16 + k4 * 4 + 1) * 128 + j],
                           mk_w[(h * 16 + k4 * 4 + 2) * 128 + j],
                           mk_w[(h * 16 + k4 * 4 + 3) * 128 + j]);
    *(float4*)&ws[OFF_MKP + x * 4] = v; return;
  }
  x -= 4096;
  if (x < 128) ws[OFF_FCC + x] = fc_w[x * 129 + 128];   // fc cap column
}

__global__ __launch_bounds__(256, 2) void decoder_loop(
    const float* __restrict__ enc, const float* __restrict__ pool,
    const float* __restrict__ capcity, const float* __restrict__ demand,
    const float* __restrict__ ws, float* __restrict__ d_out) {
  const float4* fcP  = (const float4*)(ws + OFF_FCP);
  const float4* fc1P = (const float4*)(ws + OFF_FC1P);
  const float4* mwP  = (const float4*)(ws + OFF_MWP);
  const float4* mvP  = (const float4*)(ws + OFF_MVP);
  const float4* FP   = (const float4*)(ws + OFF_FP);
  const float4* mkP  = (const float4*)(ws + OFF_MKP);

  __shared__ BS S;

  const int tl   = threadIdx.x;       // 0..255
  const int j    = tl & 127;
  const int half = tl >> 7;           // 0..1, wave-pair uniform
  const int myb  = blockIdx.x;
  const float NEG_INF = -__builtin_inff();
  const float cap0 = capcity[0];

  // ---- stage enc slice into LDS ----
  {
    const float* src = enc + (size_t)myb * NNODE * DIM;
    for (int x = tl; x < NNODE * 32; x += 256) {
      int n = x >> 5, c = x & 31;
      *(float4*)&EL(n, c * 4) = *(const float4*)(src + (size_t)n * DIM + c * 4);
    }
  }

  // ---- permanent register-resident fc (waves 0-1) / fc1 (waves 2-3) ----
  const float4* myP = (half == 0) ? fcP : fc1P;
  float4 fcReg[32];
  #pragma unroll
  for (int t = 0; t < 32; ++t) fcReg[t] = myP[t * 128 + j];
  const float fccReg = ws[OFF_FCC + j];   // fc cap column (step-invariant)

  __syncthreads();

  // ---- init carry ----
  if (tl < 128) {
    S.in_[tl] = EL(0, tl);
    S.pl[tl]  = pool[(size_t)myb * DIM + tl];
  }
  if (tl < NNODE) S.dem[tl] = demand[(size_t)myb * NNODE + tl];
  if (tl == 0) { S.cap = capcity[myb]; S.lp = 0.f; S.idx = 0; }
  __syncthreads();
  if (tl < NNODE) {
    float v1 = (tl == 0) ? 1.f : 0.f;
    S.mask1[tl] = v1;
    S.mask[tl] = (S.dem[tl] > S.cap) ? 1.f : v1;
  }
  __syncthreads();
  if (tl < 64) {
    bool ok = (tl == 0) || (S.mask[tl] > 0.5f);
    if (tl + 64 < NNODE) ok = ok && (S.mask[tl + 64] > 0.5f);
    bool alld = __all(ok);
    if (alld && tl == 0) S.mask[0] = 0.f;
  }
  __syncthreads();

  for (int step = 0; step < NSTEP; ++step) {
    const float capR = S.cap;
    float4 mwPre[16];   // waves 0-1: prefetched during PH1
    float4 mkPre[16];   // waves 2-3: prefetched during PH2
    float4 mvPre[16];   // waves 2-3: prefetched during PH4
    float4 fPre[16];    // waves 2-3: prefetched during PH5b

    // PH1: waves 0-1: fc ; waves 2-3: fc1 — fully register-resident weights.
    {
      const float4* x4 = (half == 0) ? (const float4*)&S.in_[0]
                                     : (const float4*)&S.pl[0];
      float A = 0.f;
      #pragma unroll
      for (int t = 0; t < 32; ++t) {
        float4 v = x4[t];
        float4 wv = fcReg[t];
        A = fmaf(v.x, wv.x, A); A = fmaf(v.y, wv.y, A);
        A = fmaf(v.z, wv.z, A); A = fmaf(v.w, wv.w, A);
      }
      if (half == 0) A = fmaf(capR, fccReg, A);
      // prefetch mw for PH2 (waves 0-1); crosses the barriers below
      if (half == 0) {
        #pragma unroll
        for (int t = 0; t < 16; ++t) mwPre[t] = mwP[t * 128 + j];
      }
      BAR();
      if (half == 0) S.dec[j] = A;
      else           S.pl[j] = A;
    }
    BAR();

    // PH2: waves 0-1: Q ; waves 2-3: idle -> prefetch mk for PH2b.
    if (half == 0) {
      const float4* d4 = (const float4*)&S.dec[0];
      const float4* p4 = (const float4*)&S.pl[0];
      float B = 0.f;
      #pragma unroll
      for (int t = 0; t < 16; ++t) {
        float4 a = d4[t], p = p4[t];
        float4 wv = mwPre[t];
        B = fmaf(a.x + p.x, wv.x, B); B = fmaf(a.y + p.y, wv.y, B);
        B = fmaf(a.z + p.z, wv.z, B); B = fmaf(a.w + p.w, wv.w, B);
      }
      #pragma unroll 8
      for (int t = 16; t < 32; ++t) {
        float4 a = d4[t], p = p4[t];
        float4 wv = mwP[t * 128 + j];
        B = fmaf(a.x + p.x, wv.x, B); B = fmaf(a.y + p.y, wv.y, B);
        B = fmaf(a.z + p.z, wv.z, B); B = fmaf(a.w + p.w, wv.w, B);
      }
      S.q[j] = B;
    } else {
      #pragma unroll
      for (int hh = 0; hh < 4; ++hh) {
        const float4* mp = mkP + ((4 + hh) * 4) * 128 + j;
        mkPre[hh * 4 + 0] = mp[0];
        mkPre[hh * 4 + 1] = mp[128];
        mkPre[hh * 4 + 2] = mp[256];
        mkPre[hh * 4 + 3] = mp[384];
      }
    }
    BAR();

    // PH2b: thread (half, j) -> heads {4*half .. 4*half+3}. Chains identical.
    {
      const float4* q4 = (const float4*)&S.q[0];
      #pragma unroll
      for (int hh = 0; hh < 4; ++hh) {
        int h = half * 4 + hh;
        float4 M0, M1, M2, M3;
        if (half == 1) {
          M0 = mkPre[hh * 4 + 0]; M1 = mkPre[hh * 4 + 1];
          M2 = mkPre[hh * 4 + 2]; M3 = mkPre[hh * 4 + 3];
        } else {
          const float4* mp = mkP + (h * 4) * 128 + j;
          M0 = mp[0]; M1 = mp[128]; M2 = mp[256]; M3 = mp[384];
        }
        float4 qa = q4[h * 4], qb = q4[h * 4 + 1], qc = q4[h * 4 + 2], qd4 = q4[h * 4 + 3];
        float acc = 0.f;
        acc = fmaf(qa.x, M0.x, acc); acc = fmaf(qa.y, M0.y, acc);
        acc = fmaf(qa.z, M0.z, acc); acc = fmaf(qa.w, M0.w, acc);
        acc = fmaf(qb.x, M1.x, acc); acc = fmaf(qb.y, M1.y, acc);
        acc = fmaf(qb.z, M1.z, acc); acc = fmaf(qb.w, M1.w, acc);
        acc = fmaf(qc.x, M2.x, acc); acc = fmaf(qc.y, M2.y, acc);
        acc = fmaf(qc.z, M2.z, acc); acc = fmaf(qc.w, M2.w, acc);
        acc = fmaf(qd4.x, M3.x, acc); acc = fmaf(qd4.y, M3.y, acc);
        acc = fmaf(qd4.z, M3.z, acc); acc = fmaf(qd4.w, M3.w, acc);
        QK(h, j) = acc;
      }
    }
    BAR();

    // PH3: ALL 256 threads (4 SIMDs): thread = (h = tl&7, nb = tl>>3).
    // Per-(h,n) chain: i4 ascending, x->y->z->w, single acc — bit-exact.
    {
      int h = tl & 7, nb = tl >> 3;   // h 0..7, nb 0..31
      float acc[4] = {0.f, 0.f, 0.f, 0.f};
      #pragma unroll 4
      for (int i4 = 0; i4 < 32; ++i4) {
        float4 q = *(const float4*)&QK(h, i4 * 4);
        #pragma unroll
        for (int p = 0; p < 4; ++p) {
          int n = p * 32 + nb;
          if (n < NNODE) {
            float4 e4 = *(const float4*)&EL(n, i4 * 4);
            acc[p] = fmaf(e4.x, q.x, acc[p]);
            acc[p] = fmaf(e4.y, q.y, acc[p]);
            acc[p] = fmaf(e4.z, q.z, acc[p]);
            acc[p] = fmaf(e4.w, q.w, acc[p]);
          }
        }
      }
      #pragma unroll
      for (int p = 0; p < 4; ++p) {
        int n = p * 32 + nb;
        if (n < NNODE) {
          float mk = S.mask[n];
          CMP(h, n) = (mk > 0.5f) ? NEG_INF : 0.25f * acc[p];
        }
      }
    }
    BAR();

    // PH4: softmax; 4 waves = head pairs. Waves 2-3 also prefetch mv.
    {
      int w = tl >> 6, lane = tl & 63;
      int hb = w * 2;
      #pragma unroll
      for (int hh = 0; hh < 2; ++hh) {
        int h = hb + hh;
        float v0 = CMP(h, lane);
        float v1 = (lane < NNODE - 64) ? CMP(h, lane + 64) : NEG_INF;
        float m = fmaxf(v0, v1);
        #pragma unroll
        for (int o = 32; o > 0; o >>= 1) m = fmaxf(m, __shfl_xor(m, o, 64));
        float e0 = expf(v0 - m);
        float e1 = (lane < NNODE - 64) ? expf(v1 - m) : 0.f;
        float ss = e0 + e1;
        #pragma unroll
        for (int o = 32; o > 0; o >>= 1) ss += __shfl_xor(ss, o, 64);
        SC(lane, h) = e0 / ss;
        if (lane < NNODE - 64) SC(lane + 64, h) = e1 / ss;
      }
    }
    if (half == 1) {
      #pragma unroll
      for (int t = 0; t < 16; ++t) mvPre[t] = mvP[t * 128 + j];
    }
    BAR();

    // PH5: ALL 256 threads: thread = (hp = tl>>6 -> head pair, j2 = tl&63).
    // Chain per (h, dim): n ascending — bit-exact.
    {
      int j2 = tl & 63, hp = tl >> 6, hb = hp * 2;
      float a00 = 0.f, a01 = 0.f, a10 = 0.f, a11 = 0.f;
      #pragma unroll 4
      for (int n = 0; n < NNODE; ++n) {
        float2 s  = *(const float2*)&SC(n, hb);
        float2 ev = *(const float2*)&EL(n, j2 * 2);
        a00 = fmaf(s.x, ev.x, a00); a01 = fmaf(s.x, ev.y, a01);
        a10 = fmaf(s.y, ev.x, a10); a11 = fmaf(s.y, ev.y, a11);
      }
      *(float2*)&ZR(hb + 0, j2 * 2) = make_float2(a00, a01);
      *(float2*)&ZR(hb + 1, j2 * 2) = make_float2(a10, a11);
    }
    BAR();

    // PH5b: waves 2-3 (hold fc1; mv prefetched): attn. One chain/thread.
    if (half == 1) {
      int h = j >> 4;
      float C = 0.f;
      #pragma unroll
      for (int t = 0; t < 16; ++t) {
        float4 z = *(const float4*)&ZR(h, t * 4);
        float4 wv = mvPre[t];
        C = fmaf(z.x, wv.x, C); C = fmaf(z.y, wv.y, C);
        C = fmaf(z.z, wv.z, C); C = fmaf(z.w, wv.w, C);
      }
      #pragma unroll 8
      for (int t = 16; t < 32; ++t) {
        float4 z = *(const float4*)&ZR(h, t * 4);
        float4 wv = mvP[t * 128 + j];
        C = fmaf(z.x, wv.x, C); C = fmaf(z.y, wv.y, C);
        C = fmaf(z.z, wv.z, C); C = fmaf(z.w, wv.w, C);
      }
      S.attn[j] = C;
      #pragma unroll
      for (int t = 0; t < 16; ++t) fPre[t] = FP[t * 128 + j];
    }
    BAR();

    // PH6: waves 2-3 (F prefetched): op. One chain/thread.
    if (half == 1) {
      const float4* x4 = (const float4*)&S.attn[0];
      float D = 0.f;
      #pragma unroll
      for (int t = 0; t < 16; ++t) {
        float4 v = x4[t];
        float4 wv = fPre[t];
        D = fmaf(v.x, wv.x, D); D = fmaf(v.y, wv.y, D);
        D = fmaf(v.z, wv.z, D); D = fmaf(v.w, wv.w, D);
      }
      #pragma unroll 8
      for (int t = 16; t < 32; ++t) {
        float4 v = x4[t];
        float4 wv = FP[t * 128 + j];
        D = fmaf(v.x, wv.x, D); D = fmaf(v.y, wv.y, D);
        D = fmaf(v.z, wv.z, D); D = fmaf(v.w, wv.w, D);
      }
      S.op[j] = D;
    }
    BAR();

    // PH7: comp2 partials — all 4 waves (bit-exact mapping)
    {
      int qd = tl & 3, nq = tl >> 2;   // nq 0..63
      #pragma unroll
      for (int p = 0; p < 2; ++p) {
        int n = p * 64 + nq;
        if (n < NNODE) {
          float acc = 0.f;
          #pragma unroll
          for (int i4 = 0; i4 < 8; ++i4) {
            float4 ov = *(const float4*)&S.op[qd * 32 + i4 * 4];
            float4 e4 = *(const float4*)&EL(n, qd * 32 + i4 * 4);
            acc = fmaf(e4.x, ov.x, acc);
            acc = fmaf(e4.y, ov.y, acc);
            acc = fmaf(e4.z, ov.z, acc);
            acc = fmaf(e4.w, ov.w, acc);
          }
          SRED(n, qd) = acc;
        }
      }
    }
    BAR();

    // PH8 merged tail: logits, argmax, logsumexp, state, mask update (wave 0).
    if (tl < 64) {
      int lane = tl;
      float4 r0 = *(const float4*)&SRED(lane, 0);
      float tot0 = (r0.x + r0.y) + (r0.z + r0.w);
      float x0 = tanhf(tot0 * NORM_PROB) * 10.f;
      float v0 = (S.mask[lane] > 0.5f) ? NEG_INF : x0;
      float v1 = NEG_INF;
      if (lane < NNODE - 64) {
        float4 r1 = *(const float4*)&SRED(lane + 64, 0);
        float tot1 = (r1.x + r1.y) + (r1.z + r1.w);
        float x1 = tanhf(tot1 * NORM_PROB) * 10.f;
        v1 = (S.mask[lane + 64] > 0.5f) ? NEG_INF : x1;
      }
      float bv; int bi;
      if (v1 > v0) { bv = v1; bi = lane + 64; } else { bv = v0; bi = lane; }
      #pragma unroll
      for (int o = 32; o > 0; o >>= 1) {
        float ov = __shfl_xor(bv, o, 64);
        int   oi = __shfl_xor(bi, o, 64);
        if (ov > bv || (ov == bv && oi < bi)) { bv = ov; bi = oi; }
      }
      float e0 = expf(v0 - bv);
      float e1 = (lane < NNODE - 64) ? expf(v1 - bv) : 0.f;
      float ss = e0 + e1;
      #pragma unroll
      for (int o = 32; o > 0; o >>= 1) ss += __shfl_xor(ss, o, 64);
      int c = 0;
      if (lane >= 1 && S.mask1[lane] > 0.5f) c++;
      if (lane + 64 < NNODE && S.mask1[lane + 64] > 0.5f) c++;
      #pragma unroll
      for (int o = 32; o > 0; o >>= 1) c += __shfl_xor(c, o, 64);
      float newcap = (bi < 1) ? cap0 : (S.cap - S.dem[bi]);
      if (lane == 0) {
        if (c < NNODE - 1) S.lp += -logf(ss);
        d_out[(size_t)myb * NSTEP + step] = (float)bi;
        S.cap = newcap;
        S.idx = bi;
      }
      float m1a;
      if (lane == 0) m1a = (bi < 1) ? 1.f : 0.f;
      else           m1a = (lane == bi) ? 1.f : S.mask1[lane];
      float ma = (S.dem[lane] > newcap) ? 1.f : m1a;
      float m1b = 0.f, mb = 1.f;
      if (lane + 64 < NNODE) {
        m1b = (lane + 64 == bi) ? 1.f : S.mask1[lane + 64];
        mb  = (S.dem[lane + 64] > newcap) ? 1.f : m1b;
      }
      bool ok = (lane == 0) || (ma > 0.5f);
      if (lane + 64 < NNODE) ok = ok && (mb > 0.5f);
      bool alld = __all(ok);
      if (alld && lane == 0) ma = 0.f;
      S.mask1[lane] = m1a;
      S.mask[lane]  = ma;
      if (lane + 64 < NNODE) { S.mask1[lane + 64] = m1b; S.mask[lane + 64] = mb; }
    }
    BAR();

    // PH9: new input row (from LDS enc)
    if (tl < 128) S.in_[tl] = EL(S.idx, tl);
    BAR();
  }

  if (tl == 0) d_out[(size_t)BTOT * NSTEP + myb] = S.lp;
}

extern "C" void kernel_launch(void* const* d_in, const int* in_sizes, int n_in,
                              void* d_out, int out_size, void* d_ws, size_t ws_size,
                              hipStream_t stream) {
  const float* enc   = (const float*)d_in[0];
  const float* pool  = (const float*)d_in[1];
  const float* cap   = (const float*)d_in[2];
  const float* dem   = (const float*)d_in[3];
  const float* fc_w  = (const float*)d_in[7];
  const float* fc1_w = (const float*)d_in[8];
  const float* pk_w  = (const float*)d_in[9];
  const float* mw_w  = (const float*)d_in[10];
  const float* mk_w  = (const float*)d_in[11];
  const float* mv_w  = (const float*)d_in[12];
  const float* mfc_w = (const float*)d_in[13];
  float* out = (float*)d_out;
  float* ws  = (float*)d_ws;

  prep_weights<<<97, 256, 0, stream>>>(fc_w, fc1_w, mw_w, mv_w, mfc_w, pk_w, mk_w, ws);
  decoder_loop<<<BTOT, 256, 0, stream>>>(enc, pool, cap, dem, ws, out);
}

// Round 5
// 9423.689 us; speedup vs baseline: 9.0275x; 9.0275x over previous
//
#include <hip/hip_runtime.h>

#define NNODE 101
#define DIM   128
#define NHEAD 8
#define NSTEP 150
#define BTOT  2048
#define ENCP  132          // padded enc row stride in LDS

// packed-weight ws layout (floats)
#define OFF_FCP   0
#define OFF_FC1P  16384
#define OFF_MWP   32768
#define OFF_MVP   49152
#define OFF_FP    65536
#define OFF_MKP   81920
#define OFF_FCC   98304
#define NORM_PROB 0.08838834764831845f

// R14 (2nd resubmit — R3/R4 benches were GPUAcquisitionTimeout, never ran):
// SIMD-balance pass on the R12 chassis (1 elem / 256 thr / 2 blocks/CU).
// R13 post-mortem: fcReg[32]+4 prefetch arrays spilled (WRITE_SIZE 1.3MB->44GB)
// -> all register-residency/prefetch reverted; plain __syncthreads throughout.
// R12 insight: every tl<128 phase runs on SIMDs 0-1 only (wave%4), so the
// heavy phases starved SIMDs 2-3 in BOTH co-resident blocks. Fixes:
//  (a) PH3 spread to 4 waves: thread=(h2=tl&3 head pair, nb=tl>>2), owns
//      nodes {nb, nb+64}; per-(h,n) chain identical -> bit-exact;
//  (b) PH5 spread to 4 waves: thread=(hp=tl>>6 head pair, j2=tl&63);
//  (c) PH5b moved to waves 2-3, PH6 on waves 0-1 (PH2 stays 0-1);
//  (d) PH9 deleted: PH1 reads enc[S.idx] directly (same bits as S.in_).
struct __align__(16) BS {
  float enc[NNODE * ENCP];              // 53,328 B
  float pl[DIM], dec[DIM], q[DIM], attn[DIM], op[DIM];
  float U[1888];                        // QK/ZR: h*132+i ; CMP: 1056+h*104+n
  float sc[1212];                       // SC: n*12+h ; SRED: n*12+k
  float mask[NNODE], mask1[NNODE], dem[NNODE];
  float cap, lp;
  int   idx;
};                                      // ~69,500 B total

#define EL(n,i)     S.enc[(n)*ENCP + (i)]
#define QK(h,i)     S.U[(h)*132 + (i)]
#define ZR(h,i)     S.U[(h)*132 + (i)]
#define CMP(h,n)    S.U[1056 + (h)*104 + (n)]
#define SC(n,h)     S.sc[(n)*12 + (h)]
#define SRED(n,k)   S.sc[(n)*12 + (k)]

// Pack all weights as float4 panels: P[i4*128 + j] = {wT[i4*4+0][j], .., wT[i4*4+3][j]}
__global__ void prep_weights(const float* __restrict__ fc_w,
                             const float* __restrict__ fc1_w,
                             const float* __restrict__ mw_w,
                             const float* __restrict__ mv_w,
                             const float* __restrict__ mfc_w,
                             const float* __restrict__ pk_w,
                             const float* __restrict__ mk_w,
                             float* __restrict__ ws) {
  int x = blockIdx.x * 256 + threadIdx.x;
  if (x < 4096) {                      // fcP
    int i4 = x >> 7, j = x & 127;
    float4 v = make_float4(fc_w[j * 129 + i4 * 4 + 0], fc_w[j * 129 + i4 * 4 + 1],
                           fc_w[j * 129 + i4 * 4 + 2], fc_w[j * 129 + i4 * 4 + 3]);
    *(float4*)&ws[OFF_FCP + x * 4] = v; return;
  }
  x -= 4096;
  if (x < 4096) {                      // fc1P
    int i4 = x >> 7, j = x & 127;
    float4 v = make_float4(fc1_w[j * 128 + i4 * 4 + 0], fc1_w[j * 128 + i4 * 4 + 1],
                           fc1_w[j * 128 + i4 * 4 + 2], fc1_w[j * 128 + i4 * 4 + 3]);
    *(float4*)&ws[OFF_FC1P + x * 4] = v; return;
  }
  x -= 4096;
  if (x < 4096) {                      // mwP
    int i4 = x >> 7, j = x & 127;
    float4 v = make_float4(mw_w[j * 128 + i4 * 4 + 0], mw_w[j * 128 + i4 * 4 + 1],
                           mw_w[j * 128 + i4 * 4 + 2], mw_w[j * 128 + i4 * 4 + 3]);
    *(float4*)&ws[OFF_MWP + x * 4] = v; return;
  }
  x -= 4096;
  if (x < 4096) {                      // mvP
    int i4 = x >> 7, j = x & 127;
    float4 v = make_float4(mv_w[j * 128 + i4 * 4 + 0], mv_w[j * 128 + i4 * 4 + 1],
                           mv_w[j * 128 + i4 * 4 + 2], mv_w[j * 128 + i4 * 4 + 3]);
    *(float4*)&ws[OFF_MVP + x * 4] = v; return;
  }
  x -= 4096;
  if (x < 4096) {                      // FP : F[i2][j] = sum_d mfc[d][i2]*pk[d][j]
    int i4 = x >> 7, j = x & 127;
    float a[4] = {0.f, 0.f, 0.f, 0.f};
    for (int d = 0; d < 128; ++d) {
      float p = pk_w[d * 128 + j];
      a[0] = fmaf(mfc_w[d * 128 + i4 * 4 + 0], p, a[0]);
      a[1] = fmaf(mfc_w[d * 128 + i4 * 4 + 1], p, a[1]);
      a[2] = fmaf(mfc_w[d * 128 + i4 * 4 + 2], p, a[2]);
      a[3] = fmaf(mfc_w[d * 128 + i4 * 4 + 3], p, a[3]);
    }
    *(float4*)&ws[OFF_FP + x * 4] = make_float4(a[0], a[1], a[2], a[3]); return;
  }
  x -= 4096;
  if (x < 4096) {                      // mkP
    int hk = x >> 7, j = x & 127;
    int h = hk >> 2, k4 = hk & 3;
    float4 v = make_float4(mk_w[(h * 16 + k4 * 4 + 0) * 128 + j],
                           mk_w[(h * 16 + k4 * 4 + 1) * 128 + j],
                           mk_w[(h * 16 + k4 * 4 + 2) * 128 + j],
                           mk_w[(h * 16 + k4 * 4 + 3) * 128 + j]);
    *(float4*)&ws[OFF_MKP + x * 4] = v; return;
  }
  x -= 4096;
  if (x < 128) ws[OFF_FCC + x] = fc_w[x * 129 + 128];   // fc cap column
}

__global__ __launch_bounds__(256, 2) void decoder_loop(
    const float* __restrict__ enc, const float* __restrict__ pool,
    const float* __restrict__ capcity, const float* __restrict__ demand,
    const float* __restrict__ ws, float* __restrict__ d_out) {
  const float4* fcP  = (const float4*)(ws + OFF_FCP);
  const float4* fc1P = (const float4*)(ws + OFF_FC1P);
  const float4* mwP  = (const float4*)(ws + OFF_MWP);
  const float4* mvP  = (const float4*)(ws + OFF_MVP);
  const float4* FP   = (const float4*)(ws + OFF_FP);
  const float4* mkP  = (const float4*)(ws + OFF_MKP);

  __shared__ BS S;

  const int tl   = threadIdx.x;       // 0..255
  const int j    = tl & 127;
  const int half = tl >> 7;           // 0..1, wave-pair uniform
  const int myb  = blockIdx.x;
  const float NEG_INF = -__builtin_inff();
  const float cap0 = capcity[0];

  // ---- stage enc slice into LDS ----
  {
    const float* src = enc + (size_t)myb * NNODE * DIM;
    for (int x = tl; x < NNODE * 32; x += 256) {
      int n = x >> 5, c = x & 31;
      *(float4*)&EL(n, c * 4) = *(const float4*)(src + (size_t)n * DIM + c * 4);
    }
  }
  __syncthreads();

  // ---- init carry ----
  if (tl < 128) S.pl[tl] = pool[(size_t)myb * DIM + tl];
  if (tl < NNODE) S.dem[tl] = demand[(size_t)myb * NNODE + tl];
  if (tl == 0) { S.cap = capcity[myb]; S.lp = 0.f; S.idx = 0; }
  __syncthreads();
  if (tl < NNODE) {
    float v1 = (tl == 0) ? 1.f : 0.f;
    S.mask1[tl] = v1;
    S.mask[tl] = (S.dem[tl] > S.cap) ? 1.f : v1;
  }
  __syncthreads();
  if (tl < 64) {
    bool ok = (tl == 0) || (S.mask[tl] > 0.5f);
    if (tl + 64 < NNODE) ok = ok && (S.mask[tl + 64] > 0.5f);
    bool alld = __all(ok);
    if (alld && tl == 0) S.mask[0] = 0.f;
  }
  __syncthreads();

  for (int step = 0; step < NSTEP; ++step) {
    const float capR = S.cap;
    const int   cidx = S.idx;

    // PH1: waves 0-1: fc from enc[cidx] (same bits as old S.in_);
    //      waves 2-3: fc1 from pl. One chain/thread — bit-exact.
    {
      const float4* x4 = (half == 0) ? (const float4*)&S.enc[cidx * ENCP]
                                     : (const float4*)&S.pl[0];
      const float4* wP = (half == 0) ? fcP : fc1P;
      float A = 0.f;
      #pragma unroll 8
      for (int t = 0; t < 32; ++t) {
        float4 v = x4[t];
        float4 wv = wP[t * 128 + j];
        A = fmaf(v.x, wv.x, A); A = fmaf(v.y, wv.y, A);
        A = fmaf(v.z, wv.z, A); A = fmaf(v.w, wv.w, A);
      }
      if (half == 0) A = fmaf(capR, ws[OFF_FCC + j], A);
      __syncthreads();
      if (half == 0) S.dec[j] = A;
      else           S.pl[j] = A;
    }
    __syncthreads();

    // PH2: waves 0-1: Q. One chain/thread; (dec+pl) inline.
    if (half == 0) {
      const float4* d4 = (const float4*)&S.dec[0];
      const float4* p4 = (const float4*)&S.pl[0];
      float B = 0.f;
      #pragma unroll 8
      for (int t = 0; t < 32; ++t) {
        float4 a = d4[t], p = p4[t];
        float4 wv = mwP[t * 128 + j];
        B = fmaf(a.x + p.x, wv.x, B); B = fmaf(a.y + p.y, wv.y, B);
        B = fmaf(a.z + p.z, wv.z, B); B = fmaf(a.w + p.w, wv.w, B);
      }
      S.q[j] = B;
    }
    __syncthreads();

    // PH2b: thread (half, j) -> heads {4*half .. 4*half+3}. Chains identical.
    {
      const float4* q4 = (const float4*)&S.q[0];
      #pragma unroll
      for (int hh = 0; hh < 4; ++hh) {
        int h = half * 4 + hh;
        const float4* mp = mkP + (h * 4) * 128 + j;
        float4 M0 = mp[0], M1 = mp[128], M2 = mp[256], M3 = mp[384];
        float4 qa = q4[h * 4], qb = q4[h * 4 + 1], qc = q4[h * 4 + 2], qd4 = q4[h * 4 + 3];
        float acc = 0.f;
        acc = fmaf(qa.x, M0.x, acc); acc = fmaf(qa.y, M0.y, acc);
        acc = fmaf(qa.z, M0.z, acc); acc = fmaf(qa.w, M0.w, acc);
        acc = fmaf(qb.x, M1.x, acc); acc = fmaf(qb.y, M1.y, acc);
        acc = fmaf(qb.z, M1.z, acc); acc = fmaf(qb.w, M1.w, acc);
        acc = fmaf(qc.x, M2.x, acc); acc = fmaf(qc.y, M2.y, acc);
        acc = fmaf(qc.z, M2.z, acc); acc = fmaf(qc.w, M2.w, acc);
        acc = fmaf(qd4.x, M3.x, acc); acc = fmaf(qd4.y, M3.y, acc);
        acc = fmaf(qd4.z, M3.z, acc); acc = fmaf(qd4.w, M3.w, acc);
        QK(h, j) = acc;
      }
    }
    __syncthreads();

    // PH3: ALL 4 waves. Thread = (h2 = tl&3 -> head pair, nb = tl>>2);
    // owns nodes {nb, nb+64}. Per-(h,n) chain: i4 ascending, x->y->z->w,
    // single acc — bit-exact vs R12.
    {
      int h2 = tl & 3, nb = tl >> 2;       // h2 0..3, nb 0..63
      int ha = h2 * 2, hb2 = h2 * 2 + 1;
      int n1 = nb + 64;
      bool has1 = (n1 < NNODE);
      float aA0 = 0.f, aB0 = 0.f, aA1 = 0.f, aB1 = 0.f;
      #pragma unroll 4
      for (int i4 = 0; i4 < 32; ++i4) {
        float4 qA = *(const float4*)&QK(ha,  i4 * 4);
        float4 qB = *(const float4*)&QK(hb2, i4 * 4);
        float4 e0 = *(const float4*)&EL(nb, i4 * 4);
        aA0 = fmaf(e0.x, qA.x, aA0); aA0 = fmaf(e0.y, qA.y, aA0);
        aA0 = fmaf(e0.z, qA.z, aA0); aA0 = fmaf(e0.w, qA.w, aA0);
        aB0 = fmaf(e0.x, qB.x, aB0); aB0 = fmaf(e0.y, qB.y, aB0);
        aB0 = fmaf(e0.z, qB.z, aB0); aB0 = fmaf(e0.w, qB.w, aB0);
        if (has1) {
          float4 e1 = *(const float4*)&EL(n1, i4 * 4);
          aA1 = fmaf(e1.x, qA.x, aA1); aA1 = fmaf(e1.y, qA.y, aA1);
          aA1 = fmaf(e1.z, qA.z, aA1); aA1 = fmaf(e1.w, qA.w, aA1);
          aB1 = fmaf(e1.x, qB.x, aB1); aB1 = fmaf(e1.y, qB.y, aB1);
          aB1 = fmaf(e1.z, qB.z, aB1); aB1 = fmaf(e1.w, qB.w, aB1);
        }
      }
      {
        float mk0 = S.mask[nb];
        CMP(ha,  nb) = (mk0 > 0.5f) ? NEG_INF : 0.25f * aA0;
        CMP(hb2, nb) = (mk0 > 0.5f) ? NEG_INF : 0.25f * aB0;
      }
      if (has1) {
        float mk1 = S.mask[n1];
        CMP(ha,  n1) = (mk1 > 0.5f) ? NEG_INF : 0.25f * aA1;
        CMP(hb2, n1) = (mk1 > 0.5f) ? NEG_INF : 0.25f * aB1;
      }
    }
    __syncthreads();

    // PH4: softmax; 4 waves = head pairs
    {
      int w = tl >> 6, lane = tl & 63;
      int hb = w * 2;
      #pragma unroll
      for (int hh = 0; hh < 2; ++hh) {
        int h = hb + hh;
        float v0 = CMP(h, lane);
        float v1 = (lane < NNODE - 64) ? CMP(h, lane + 64) : NEG_INF;
        float m = fmaxf(v0, v1);
        #pragma unroll
        for (int o = 32; o > 0; o >>= 1) m = fmaxf(m, __shfl_xor(m, o, 64));
        float e0 = expf(v0 - m);
        float e1 = (lane < NNODE - 64) ? expf(v1 - m) : 0.f;
        float ss = e0 + e1;
        #pragma unroll
        for (int o = 32; o > 0; o >>= 1) ss += __shfl_xor(ss, o, 64);
        SC(lane, h) = e0 / ss;
        if (lane < NNODE - 64) SC(lane + 64, h) = e1 / ss;
      }
    }
    __syncthreads();

    // PH5: ALL 4 waves. Thread = (hp = tl>>6 -> head pair, j2 = tl&63).
    // Chain per (h, dim): n ascending — bit-exact.
    {
      int j2 = tl & 63, hp = tl >> 6, hb = hp * 2;
      float a00 = 0.f, a01 = 0.f, a10 = 0.f, a11 = 0.f;
      #pragma unroll 4
      for (int n = 0; n < NNODE; ++n) {
        float2 s  = *(const float2*)&SC(n, hb);
        float2 ev = *(const float2*)&EL(n, j2 * 2);
        a00 = fmaf(s.x, ev.x, a00); a01 = fmaf(s.x, ev.y, a01);
        a10 = fmaf(s.y, ev.x, a10); a11 = fmaf(s.y, ev.y, a11);
      }
      *(float2*)&ZR(hb + 0, j2 * 2) = make_float2(a00, a01);
      *(float2*)&ZR(hb + 1, j2 * 2) = make_float2(a10, a11);
    }
    __syncthreads();

    // PH5b: waves 2-3: attn. One chain/thread.
    if (half == 1) {
      int h = j >> 4;
      float C = 0.f;
      #pragma unroll 8
      for (int t = 0; t < 32; ++t) {
        float4 z = *(const float4*)&ZR(h, t * 4);
        float4 wv = mvP[t * 128 + j];
        C = fmaf(z.x, wv.x, C); C = fmaf(z.y, wv.y, C);
        C = fmaf(z.z, wv.z, C); C = fmaf(z.w, wv.w, C);
      }
      S.attn[j] = C;
    }
    __syncthreads();

    // PH6: waves 0-1: op. One chain/thread.
    if (half == 0) {
      const float4* x4 = (const float4*)&S.attn[0];
      float D = 0.f;
      #pragma unroll 8
      for (int t = 0; t < 32; ++t) {
        float4 v = x4[t];
        float4 wv = FP[t * 128 + j];
        D = fmaf(v.x, wv.x, D); D = fmaf(v.y, wv.y, D);
        D = fmaf(v.z, wv.z, D); D = fmaf(v.w, wv.w, D);
      }
      S.op[j] = D;
    }
    __syncthreads();

    // PH7: comp2 partials — all 4 waves (bit-exact mapping)
    {
      int qd = tl & 3, nq = tl >> 2;   // nq 0..63
      #pragma unroll
      for (int p = 0; p < 2; ++p) {
        int n = p * 64 + nq;
        if (n < NNODE) {
          float acc = 0.f;
          #pragma unroll
          for (int i4 = 0; i4 < 8; ++i4) {
            float4 ov = *(const float4*)&S.op[qd * 32 + i4 * 4];
            float4 e4 = *(const float4*)&EL(n, qd * 32 + i4 * 4);
            acc = fmaf(e4.x, ov.x, acc);
            acc = fmaf(e4.y, ov.y, acc);
            acc = fmaf(e4.z, ov.z, acc);
            acc = fmaf(e4.w, ov.w, acc);
          }
          SRED(n, qd) = acc;
        }
      }
    }
    __syncthreads();

    // PH8 merged tail: logits, argmax, logsumexp, state, mask update (wave 0).
    if (tl < 64) {
      int lane = tl;
      float4 r0 = *(const float4*)&SRED(lane, 0);
      float tot0 = (r0.x + r0.y) + (r0.z + r0.w);
      float x0 = tanhf(tot0 * NORM_PROB) * 10.f;
      float v0 = (S.mask[lane] > 0.5f) ? NEG_INF : x0;
      float v1 = NEG_INF;
      if (lane < NNODE - 64) {
        float4 r1 = *(const float4*)&SRED(lane + 64, 0);
        float tot1 = (r1.x + r1.y) + (r1.z + r1.w);
        float x1 = tanhf(tot1 * NORM_PROB) * 10.f;
        v1 = (S.mask[lane + 64] > 0.5f) ? NEG_INF : x1;
      }
      float bv; int bi;
      if (v1 > v0) { bv = v1; bi = lane + 64; } else { bv = v0; bi = lane; }
      #pragma unroll
      for (int o = 32; o > 0; o >>= 1) {
        float ov = __shfl_xor(bv, o, 64);
        int   oi = __shfl_xor(bi, o, 64);
        if (ov > bv || (ov == bv && oi < bi)) { bv = ov; bi = oi; }
      }
      float e0 = expf(v0 - bv);
      float e1 = (lane < NNODE - 64) ? expf(v1 - bv) : 0.f;
      float ss = e0 + e1;
      #pragma unroll
      for (int o = 32; o > 0; o >>= 1) ss += __shfl_xor(ss, o, 64);
      int c = 0;
      if (lane >= 1 && S.mask1[lane] > 0.5f) c++;
      if (lane + 64 < NNODE && S.mask1[lane + 64] > 0.5f) c++;
      #pragma unroll
      for (int o = 32; o > 0; o >>= 1) c += __shfl_xor(c, o, 64);
      float newcap = (bi < 1) ? cap0 : (S.cap - S.dem[bi]);
      if (lane == 0) {
        if (c < NNODE - 1) S.lp += -logf(ss);
        d_out[(size_t)myb * NSTEP + step] = (float)bi;
        S.cap = newcap;
        S.idx = bi;
      }
      float m1a;
      if (lane == 0) m1a = (bi < 1) ? 1.f : 0.f;
      else           m1a = (lane == bi) ? 1.f : S.mask1[lane];
      float ma = (S.dem[lane] > newcap) ? 1.f : m1a;
      float m1b = 0.f, mb = 1.f;
      if (lane + 64 < NNODE) {
        m1b = (lane + 64 == bi) ? 1.f : S.mask1[lane + 64];
        mb  = (S.dem[lane + 64] > newcap) ? 1.f : m1b;
      }
      bool ok = (lane == 0) || (ma > 0.5f);
      if (lane + 64 < NNODE) ok = ok && (mb > 0.5f);
      bool alld = __all(ok);
      if (alld && lane == 0) ma = 0.f;
      S.mask1[lane] = m1a;
      S.mask[lane]  = ma;
      if (lane + 64 < NNODE) { S.mask1[lane + 64] = m1b; S.mask[lane + 64] = mb; }
    }
    __syncthreads();
  }

  if (tl == 0) d_out[(size_t)BTOT * NSTEP + myb] = S.lp;
}

extern "C" void kernel_launch(void* const* d_in, const int* in_sizes, int n_in,
                              void* d_out, int out_size, void* d_ws, size_t ws_size,
                              hipStream_t stream) {
  const float* enc   = (const float*)d_in[0];
  const float* pool  = (const float*)d_in[1];
  const float* cap   = (const float*)d_in[2];
  const float* dem   = (const float*)d_in[3];
  const float* fc_w  = (const float*)d_in[7];
  const float* fc1_w = (const float*)d_in[8];
  const float* pk_w  = (const float*)d_in[9];
  const float* mw_w  = (const float*)d_in[10];
  const float* mk_w  = (const float*)d_in[11];
  const float* mv_w  = (const float*)d_in[12];
  const float* mfc_w = (const float*)d_in[13];
  float* out = (float*)d_out;
  float* ws  = (float*)d_ws;

  prep_weights<<<97, 256, 0, stream>>>(fc_w, fc1_w, mw_w, mv_w, mfc_w, pk_w, mk_w, ws);
  decoder_loop<<<BTOT, 256, 0, stream>>>(enc, pool, cap, dem, ws, out);
}